// Round 9
// baseline (181.615 us; speedup 1.0000x reference)
//
#include <hip/hip_runtime.h>
#include <math.h>

#if defined(__has_builtin)
#  if __has_builtin(__builtin_amdgcn_exp2f)
#    define EXP2F(x) __builtin_amdgcn_exp2f(x)
#  else
#    define EXP2F(x) exp2f(x)
#  endif
#else
#  define EXP2F(x) exp2f(x)
#endif

constexpr int   DD = 16;
constexpr float T2 = 72.13475204444817f;   // 50/ln2
constexpr float DEFER_THR = 8.0f;          // T13 defer-max

typedef __attribute__((ext_vector_type(8)))  short s16x8;
typedef __attribute__((ext_vector_type(16))) float f32x16;

static __device__ __forceinline__ s16x8 mk8(unsigned a, unsigned b, unsigned c, unsigned d) {
    union { unsigned u[4]; s16x8 v; } x;
    x.u[0] = a; x.u[1] = b; x.u[2] = c; x.u[3] = d;
    return x.v;
}
static __device__ __forceinline__ unsigned pack_tr(float a, float b) {
    return (__float_as_uint(a) >> 16) | (__float_as_uint(b) & 0xFFFF0000u);
}
static __device__ __forceinline__ float trunc_bf(float a) {
    return __uint_as_float(__float_as_uint(a) & 0xFFFF0000u);
}
static __device__ __forceinline__ unsigned short rne16(float f) {
    unsigned u = __float_as_uint(f);
    return (unsigned short)((u + 0x7FFFu + ((u >> 16) & 1u)) >> 16);
}
static __device__ __forceinline__ float bfh2f(unsigned short h) {
    return __uint_as_float(((unsigned)h) << 16);
}

// ---------- prep: fully parallel (1 thread / output element).
// Threads [0,C): Y-row hi/lo split (contiguous 16B stores) + Bq.
// Threads [C, C+32C): one V3h element each: V3h[t][r][slot], rows 0..15 = dims,
// 16 = b, 17 = 1.0, 18..31 = 0; slot crow-permuted within tile (verified layout). ----------
__global__ void prep_kernel(const float* __restrict__ Y, const float* __restrict__ B,
                            unsigned short* __restrict__ YhA, unsigned short* __restrict__ YlA,
                            unsigned short* __restrict__ V3h, unsigned* __restrict__ Bq, int C)
{
    int gid = blockIdx.x * blockDim.x + threadIdx.x;
    if (gid < C) {
        const int c = gid;
        union { unsigned short u[DD]; s16x8 v[2]; } hb, lb;
        const float* yr = Y + (size_t)c * DD;
#pragma unroll
        for (int d = 0; d < DD; ++d) {
            float y = yr[d];
            unsigned short h = rne16(y);
            hb.u[d] = h;
            lb.u[d] = rne16(y - bfh2f(h));
        }
        s16x8* yh = (s16x8*)(YhA + (size_t)c * DD);
        s16x8* yl = (s16x8*)(YlA + (size_t)c * DD);
        yh[0] = hb.v[0]; yh[1] = hb.v[1];
        yl[0] = lb.v[0]; yl[1] = lb.v[1];

        float qb = -T2 * B[c];
        unsigned short qh = rne16(qb);
        Bq[c] = (unsigned)qh | ((unsigned)rne16(qb - bfh2f(qh)) << 16);
    } else if (gid < C + 32 * C) {
        const int e = gid - C;
        const int t = e >> 10, r = (e >> 5) & 31, slot = e & 31;
        int j = slot & 7, hs = (slot >> 3) & 1;
        int cl = (slot & 16) | (j & 3) | (hs << 2) | (((j >> 2) & 1) << 3);
        int cc = (t << 5) | cl;
        float v;
        if (r < DD)           v = Y[(size_t)cc * DD + r];
        else if (r == DD)     v = B[cc];     // row16 = b
        else if (r == DD + 1) v = 1.0f;      // row17 = 1
        else                  v = 0.0f;
        V3h[((size_t)t * 32 + r) * 32 + slot] = rne16(v);
    }
}

struct Frag {
    s16x8 aYh, aYl, vh0, vh1;
    unsigned bw;
};

// ---------- main: flash softmax-matmul, 32 samples/block, 8 waves split C (max occupancy) ----------
__global__ __launch_bounds__(512, 8)
void finite_mfma(const float* __restrict__ X,
                 const unsigned short* __restrict__ YhA, const unsigned short* __restrict__ YlA,
                 const unsigned short* __restrict__ V3h, const unsigned* __restrict__ Bq,
                 float* __restrict__ out, int N, int C)
{
    const int tid  = threadIdx.x;
    const int wave = tid >> 6, lane = tid & 63;
    const int s = lane & 31, hi = lane >> 5;
    const int n0 = blockIdx.x * 32;
    const int cpw = C >> 3, cbase = wave * cpw, ntile = cpw >> 5;   // 256 cands, 8 tiles

    __shared__ float bufc[8][18][32];
    __shared__ float lds_m[8][32];

    // streaming pointers; tile strides: Y 512 shorts, V3 1024 shorts, Bq 32 words
    const unsigned short* pYh = YhA + ((size_t)(cbase + s) * DD + 8 * hi);
    const unsigned short* pYl = YlA + ((size_t)(cbase + s) * DD + 8 * hi);
    const unsigned short* pVh = V3h + (((size_t)(cbase >> 5) * 32 + s) * 32 + 8 * hi);
    const unsigned*       pBq = Bq + cbase + s;

    // X row for sample n0+s, this half's 8 dims, T2-scaled, trunc-split to bf16 hi/lo
    const float* xp = X + ((size_t)(n0 + s) * DD + 8 * hi);
    float xq[8];
#pragma unroll
    for (int jj = 0; jj < 8; ++jj) xq[jj] = xp[jj] * T2;
    unsigned xhw[4], xlw[4];
#pragma unroll
    for (int jj = 0; jj < 4; ++jj) {
        float a = xq[2 * jj], b = xq[2 * jj + 1];
        xhw[jj] = pack_tr(a, b);
        xlw[jj] = pack_tr(a - trunc_bf(a), b - trunc_bf(b));
    }
    const s16x8 xqh = mk8(xhw[0], xhw[1], xhw[2], xhw[3]);
    const s16x8 xql = mk8(xlw[0], xlw[1], xlw[2], xlw[3]);
    const s16x8 ones2 = mk8(hi ? 0u : 0x3F803F80u, 0u, 0u, 0u);

    f32x16 acc;
#pragma unroll
    for (int r = 0; r < 16; ++r) acc[r] = 0.0f;
    float m2 = -INFINITY;

#define LDF(F, k) do {                                              \
        (F).aYh = *(const s16x8*)(pYh + (size_t)(k) * 512);         \
        (F).aYl = *(const s16x8*)(pYl + (size_t)(k) * 512);         \
        (F).vh0 = *(const s16x8*)(pVh + (size_t)(k) * 1024);        \
        (F).vh1 = *(const s16x8*)(pVh + (size_t)(k) * 1024 + 16);   \
        (F).bw  = pBq[(size_t)(k) * 32];                            \
    } while (0)

#define PROC(F) do {                                                            \
        const s16x8 a2 = mk8(hi ? 0u : (F).bw, 0u, 0u, 0u);                     \
        f32x16 S;                                                               \
        _Pragma("unroll")                                                       \
        for (int r = 0; r < 16; ++r) S[r] = 0.0f;                               \
        S = __builtin_amdgcn_mfma_f32_32x32x16_bf16(a2,     ones2, S, 0, 0, 0); \
        S = __builtin_amdgcn_mfma_f32_32x32x16_bf16((F).aYh, xqh,  S, 0, 0, 0); \
        S = __builtin_amdgcn_mfma_f32_32x32x16_bf16((F).aYh, xql,  S, 0, 0, 0); \
        S = __builtin_amdgcn_mfma_f32_32x32x16_bf16((F).aYl, xqh,  S, 0, 0, 0); \
        float tm[8];                                                            \
        _Pragma("unroll")                                                       \
        for (int jj = 0; jj < 8; ++jj) tm[jj] = fmaxf(S[2 * jj], S[2 * jj + 1]);\
        _Pragma("unroll")                                                       \
        for (int jj = 0; jj < 4; ++jj) tm[jj] = fmaxf(tm[jj], tm[jj + 4]);      \
        tm[0] = fmaxf(fmaxf(tm[0], tm[2]), fmaxf(tm[1], tm[3]));                \
        float tmax = fmaxf(tm[0], __shfl_xor(tm[0], 32, 64));                   \
        if (__any(tmax > m2 + DEFER_THR)) {                                     \
            float nm = fmaxf(m2, tmax);                                         \
            float sc = EXP2F(m2 - nm);                                          \
            _Pragma("unroll")                                                   \
            for (int r = 0; r < 16; ++r) acc[r] *= sc;                          \
            m2 = nm;                                                            \
        }                                                                       \
        unsigned phw[8];                                                        \
        _Pragma("unroll")                                                       \
        for (int jj = 0; jj < 8; ++jj) {                                        \
            float e0 = EXP2F(S[2 * jj] - m2);                                   \
            float e1 = EXP2F(S[2 * jj + 1] - m2);                               \
            phw[jj] = pack_tr(e0, e1);                                          \
        }                                                                       \
        const s16x8 Bph0 = mk8(phw[0], phw[1], phw[2], phw[3]);                 \
        const s16x8 Bph1 = mk8(phw[4], phw[5], phw[6], phw[7]);                 \
        acc = __builtin_amdgcn_mfma_f32_32x32x16_bf16((F).vh0, Bph0, acc, 0, 0, 0); \
        acc = __builtin_amdgcn_mfma_f32_32x32x16_bf16((F).vh1, Bph1, acc, 0, 0, 0); \
    } while (0)

    // depth-1 register prefetch (compiler may sink; 8 waves/SIMD TLP is the main cover)
    Frag f0, f1;
    LDF(f0, 0);
    for (int t = 0; t < ntile; t += 2) {
        LDF(f1, t + 1);
        PROC(f0);
        if (t + 2 < ntile) LDF(f0, t + 2);
        PROC(f1);
    }
#undef LDF
#undef PROC

    // --- block combine across the 8 candidate ranges ---
    if (hi == 0) lds_m[wave][s] = m2;
    __syncthreads();
    float mstar = lds_m[0][s];
#pragma unroll
    for (int w = 1; w < 8; ++w) mstar = fmaxf(mstar, lds_m[w][s]);
    float sw = EXP2F(m2 - mstar);
#pragma unroll
    for (int r = 0; r < 8; ++r) {                       // dv rows 0..15
        int dv = (r & 3) + 8 * (r >> 2) + 4 * hi;
        bufc[wave][dv][s] = acc[r] * sw;
    }
    if (hi == 0) {                                      // dv16 = sum e*b (acc[8]), dv17 = l (acc[9])
        bufc[wave][16][s] = acc[8] * sw;
        bufc[wave][17][s] = acc[9] * sw;
    }
    __syncthreads();

#pragma unroll
    for (int q = 0; q < 2; ++q) {
        int u = tid + 512 * q;
        if (u < 18 * 32) {
            int dv = u >> 5, ss = u & 31;
            float sum = bufc[0][dv][ss];
#pragma unroll
            for (int w = 1; w < 8; ++w) sum += bufc[w][dv][ss];
            bufc[0][dv][ss] = sum;
        }
    }
    __syncthreads();

    {   // choice: 512 threads = exactly 32 samples x 16 dims, contiguous store
        int ss = tid >> 4, d0 = tid & 15;
        float inv = 1.0f / bufc[0][17][ss];
        out[(size_t)(n0 + ss) * DD + d0] = bufc[0][d0][ss] * inv;
    }
    if (tid < 32) {
        float inv = 1.0f / bufc[0][17][tid];
        const float* xr = X + (size_t)(n0 + tid) * DD;
        float dot = 0.0f;
#pragma unroll
        for (int d = 0; d < DD; ++d) dot = fmaf(xr[d], bufc[0][d][tid], dot);
        out[(size_t)N * DD + n0 + tid] = (dot - bufc[0][16][tid]) * inv;
    }
}

extern "C" void kernel_launch(void* const* d_in, const int* in_sizes, int n_in,
                              void* d_out, int out_size, void* d_ws, size_t ws_size,
                              hipStream_t stream) {
    const float* X = (const float*)d_in[0];
    const float* Y = (const float*)d_in[1];
    const float* B = (const float*)d_in[2];
    float*     out = (float*)d_out;

    const int N = in_sizes[0] / DD;    // 32768
    const int C = in_sizes[2];         // 2048

    char* w = (char*)d_ws;
    unsigned short* YhA = (unsigned short*)(w);
    unsigned short* YlA = (unsigned short*)(w + (size_t)C * DD * 2);
    unsigned short* V3h = (unsigned short*)(w + (size_t)C * DD * 4);
    unsigned*       Bq  = (unsigned*)   (w + (size_t)C * DD * 4 + (size_t)32 * C * 2);

    const int prep_threads = C + 32 * C;
    hipLaunchKernelGGL(prep_kernel, dim3((prep_threads + 255) / 256), dim3(256), 0, stream,
                       Y, B, YhA, YlA, V3h, Bq, C);
    hipLaunchKernelGGL(finite_mfma, dim3(N / 32), dim3(512), 0, stream,
                       X, YhA, YlA, V3h, Bq, out, N, C);
}

// Round 12
// 83.383 us; speedup vs baseline: 2.1781x; 2.1781x over previous
//
#include <hip/hip_runtime.h>
#include <math.h>

#if defined(__has_builtin)
#  if __has_builtin(__builtin_amdgcn_exp2f)
#    define EXP2F(x) __builtin_amdgcn_exp2f(x)
#  else
#    define EXP2F(x) exp2f(x)
#  endif
#else
#  define EXP2F(x) exp2f(x)
#endif

constexpr int   DD = 16;
constexpr float T2 = 72.13475204444817f;   // 50/ln2
constexpr float DEFER_THR = 8.0f;          // T13 defer-max

typedef __attribute__((ext_vector_type(8)))  short s16x8;
typedef __attribute__((ext_vector_type(16))) float f32x16;

static __device__ __forceinline__ s16x8 mk8(unsigned a, unsigned b, unsigned c, unsigned d) {
    union { unsigned u[4]; s16x8 v; } x;
    x.u[0] = a; x.u[1] = b; x.u[2] = c; x.u[3] = d;
    return x.v;
}
static __device__ __forceinline__ unsigned pack_tr(float a, float b) {
    return (__float_as_uint(a) >> 16) | (__float_as_uint(b) & 0xFFFF0000u);
}
static __device__ __forceinline__ float trunc_bf(float a) {
    return __uint_as_float(__float_as_uint(a) & 0xFFFF0000u);
}
static __device__ __forceinline__ unsigned short rne16(float f) {
    unsigned u = __float_as_uint(f);
    return (unsigned short)((u + 0x7FFFu + ((u >> 16) & 1u)) >> 16);
}
static __device__ __forceinline__ float bfh2f(unsigned short h) {
    return __uint_as_float(((unsigned)h) << 16);
}

// ---------- prep: fully parallel (1 thread / output element), r9-verified ----------
__global__ void prep_kernel(const float* __restrict__ Y, const float* __restrict__ B,
                            unsigned short* __restrict__ YhA, unsigned short* __restrict__ YlA,
                            unsigned short* __restrict__ V3h, unsigned* __restrict__ Bq, int C)
{
    int gid = blockIdx.x * blockDim.x + threadIdx.x;
    if (gid < C) {
        const int c = gid;
        union { unsigned short u[DD]; s16x8 v[2]; } hb, lb;
        const float* yr = Y + (size_t)c * DD;
#pragma unroll
        for (int d = 0; d < DD; ++d) {
            float y = yr[d];
            unsigned short h = rne16(y);
            hb.u[d] = h;
            lb.u[d] = rne16(y - bfh2f(h));
        }
        s16x8* yh = (s16x8*)(YhA + (size_t)c * DD);
        s16x8* yl = (s16x8*)(YlA + (size_t)c * DD);
        yh[0] = hb.v[0]; yh[1] = hb.v[1];
        yl[0] = lb.v[0]; yl[1] = lb.v[1];

        float qb = -T2 * B[c];
        unsigned short qh = rne16(qb);
        Bq[c] = (unsigned)qh | ((unsigned)rne16(qb - bfh2f(qh)) << 16);
    } else if (gid < C + 32 * C) {
        const int e = gid - C;
        const int t = e >> 10, r = (e >> 5) & 31, slot = e & 31;
        int j = slot & 7, hs = (slot >> 3) & 1;
        int cl = (slot & 16) | (j & 3) | (hs << 2) | (((j >> 2) & 1) << 3);
        int cc = (t << 5) | cl;
        float v;
        if (r < DD)           v = Y[(size_t)cc * DD + r];
        else if (r == DD)     v = B[cc];     // row16 = b
        else if (r == DD + 1) v = 1.0f;      // row17 = 1
        else                  v = 0.0f;
        V3h[((size_t)t * 32 + r) * 32 + slot] = rne16(v);
    }
}

struct Frag {
    s16x8 aYh, aYl, vh0, vh1;
    unsigned bw;
};

// ---------- partial pass: 32 samples x 1024 cands per block; grid (N/32, 2) ----------
__global__ __launch_bounds__(256, 4)
void finite_part(const float* __restrict__ X,
                 const unsigned short* __restrict__ YhA, const unsigned short* __restrict__ YlA,
                 const unsigned short* __restrict__ V3h, const unsigned* __restrict__ Bq,
                 float* __restrict__ Part, int N, int C)
{
    const int tid  = threadIdx.x;
    const int wave = tid >> 6, lane = tid & 63;
    const int s = lane & 31, hi = lane >> 5;
    const int n0 = blockIdx.x * 32;
    const int half = blockIdx.y;
    const int cpw = C >> 3;                         // 256 cands per wave
    const int cbase = (half * 4 + wave) * cpw;
    const int ntile = cpw >> 5;                     // 8 tiles

    __shared__ float bufc[4][18][32];
    __shared__ float lds_m[4][32];

    const unsigned short* pYh = YhA + ((size_t)(cbase + s) * DD + 8 * hi);
    const unsigned short* pYl = YlA + ((size_t)(cbase + s) * DD + 8 * hi);
    const unsigned short* pVh = V3h + (((size_t)(cbase >> 5) * 32 + s) * 32 + 8 * hi);
    const unsigned*       pBq = Bq + cbase + s;

    const float* xp = X + ((size_t)(n0 + s) * DD + 8 * hi);
    float xq[8];
#pragma unroll
    for (int jj = 0; jj < 8; ++jj) xq[jj] = xp[jj] * T2;
    unsigned xhw[4], xlw[4];
#pragma unroll
    for (int jj = 0; jj < 4; ++jj) {
        float a = xq[2 * jj], b = xq[2 * jj + 1];
        xhw[jj] = pack_tr(a, b);
        xlw[jj] = pack_tr(a - trunc_bf(a), b - trunc_bf(b));
    }
    const s16x8 xqh = mk8(xhw[0], xhw[1], xhw[2], xhw[3]);
    const s16x8 xql = mk8(xlw[0], xlw[1], xlw[2], xlw[3]);
    const s16x8 ones2 = mk8(hi ? 0u : 0x3F803F80u, 0u, 0u, 0u);

    f32x16 acc;
#pragma unroll
    for (int r = 0; r < 16; ++r) acc[r] = 0.0f;
    float m2 = -INFINITY;

#define LDF(F, k) do {                                              \
        (F).aYh = *(const s16x8*)(pYh + (size_t)(k) * 512);         \
        (F).aYl = *(const s16x8*)(pYl + (size_t)(k) * 512);         \
        (F).vh0 = *(const s16x8*)(pVh + (size_t)(k) * 1024);        \
        (F).vh1 = *(const s16x8*)(pVh + (size_t)(k) * 1024 + 16);   \
        (F).bw  = pBq[(size_t)(k) * 32];                            \
    } while (0)

#define PROC(F) do {                                                            \
        const s16x8 a2 = mk8(hi ? 0u : (F).bw, 0u, 0u, 0u);                     \
        f32x16 S;                                                               \
        _Pragma("unroll")                                                       \
        for (int r = 0; r < 16; ++r) S[r] = 0.0f;                               \
        S = __builtin_amdgcn_mfma_f32_32x32x16_bf16(a2,     ones2, S, 0, 0, 0); \
        S = __builtin_amdgcn_mfma_f32_32x32x16_bf16((F).aYh, xqh,  S, 0, 0, 0); \
        S = __builtin_amdgcn_mfma_f32_32x32x16_bf16((F).aYh, xql,  S, 0, 0, 0); \
        S = __builtin_amdgcn_mfma_f32_32x32x16_bf16((F).aYl, xqh,  S, 0, 0, 0); \
        float tm[8];                                                            \
        _Pragma("unroll")                                                       \
        for (int jj = 0; jj < 8; ++jj) tm[jj] = fmaxf(S[2 * jj], S[2 * jj + 1]);\
        _Pragma("unroll")                                                       \
        for (int jj = 0; jj < 4; ++jj) tm[jj] = fmaxf(tm[jj], tm[jj + 4]);      \
        tm[0] = fmaxf(fmaxf(tm[0], tm[2]), fmaxf(tm[1], tm[3]));                \
        float tmax = fmaxf(tm[0], __shfl_xor(tm[0], 32, 64));                   \
        if (__any(tmax > m2 + DEFER_THR)) {                                     \
            float nm = fmaxf(m2, tmax);                                         \
            float sc = EXP2F(m2 - nm);                                          \
            _Pragma("unroll")                                                   \
            for (int r = 0; r < 16; ++r) acc[r] *= sc;                          \
            m2 = nm;                                                            \
        }                                                                       \
        unsigned phw[8];                                                        \
        _Pragma("unroll")                                                       \
        for (int jj = 0; jj < 8; ++jj) {                                        \
            float e0 = EXP2F(S[2 * jj] - m2);                                   \
            float e1 = EXP2F(S[2 * jj + 1] - m2);                               \
            phw[jj] = pack_tr(e0, e1);                                          \
        }                                                                       \
        const s16x8 Bph0 = mk8(phw[0], phw[1], phw[2], phw[3]);                 \
        const s16x8 Bph1 = mk8(phw[4], phw[5], phw[6], phw[7]);                 \
        acc = __builtin_amdgcn_mfma_f32_32x32x16_bf16((F).vh0, Bph0, acc, 0, 0, 0); \
        acc = __builtin_amdgcn_mfma_f32_32x32x16_bf16((F).vh1, Bph1, acc, 0, 0, 0); \
    } while (0)

    Frag f0, f1;
    LDF(f0, 0);
    for (int t = 0; t < ntile; t += 2) {
        LDF(f1, t + 1);
        PROC(f0);
        if (t + 2 < ntile) LDF(f0, t + 2);
        PROC(f1);
    }
#undef LDF
#undef PROC

    // combine this block's 4 waves
    if (hi == 0) lds_m[wave][s] = m2;
    __syncthreads();
    float mstar = fmaxf(fmaxf(lds_m[0][s], lds_m[1][s]), fmaxf(lds_m[2][s], lds_m[3][s]));
    float sw = EXP2F(m2 - mstar);
#pragma unroll
    for (int r = 0; r < 8; ++r) {
        int dv = (r & 3) + 8 * (r >> 2) + 4 * hi;
        bufc[wave][dv][s] = acc[r] * sw;
    }
    if (hi == 0) {
        bufc[wave][16][s] = acc[8] * sw;   // sum e*b
        bufc[wave][17][s] = acc[9] * sw;   // l
    }
    __syncthreads();
#pragma unroll
    for (int q = 0; q < 3; ++q) {
        int u = tid + 256 * q;
        if (u < 18 * 32) {
            int dv = u >> 5, ss = u & 31;
            bufc[0][dv][ss] = bufc[0][dv][ss] + bufc[1][dv][ss]
                            + bufc[2][dv][ss] + bufc[3][dv][ss];
        }
    }
    __syncthreads();

    // write partial: rows 0..17 = combined S, row 18 = mstar
    float* pp = Part + ((size_t)blockIdx.x * 2 + half) * 19 * 32;
#pragma unroll
    for (int q = 0; q < 3; ++q) {
        int u = tid + 256 * q;
        if (u < 19 * 32) {
            int r = u >> 5, ss = u & 31;
            float val = (r < 18) ? bufc[0][r][ss]
                                 : fmaxf(fmaxf(lds_m[0][ss], lds_m[1][ss]),
                                         fmaxf(lds_m[2][ss], lds_m[3][ss]));
            pp[u] = val;
        }
    }
}

// ---------- combine: merge the 2 halves, normalize, f_x ----------
__global__ __launch_bounds__(256)
void finite_comb(const float* __restrict__ X, const float* __restrict__ Part,
                 float* __restrict__ out, int N)
{
    const int tid = threadIdx.x;
    const int b = blockIdx.x, n0 = b * 32;
    __shared__ float S[18][32];
    __shared__ float w01[2][32];

    const float* P0 = Part + ((size_t)b * 2 + 0) * 19 * 32;
    const float* P1 = Part + ((size_t)b * 2 + 1) * 19 * 32;

    if (tid < 32) {
        float m0 = P0[18 * 32 + tid], m1 = P1[18 * 32 + tid];
        float ms = fmaxf(m0, m1);
        w01[0][tid] = EXP2F(m0 - ms);
        w01[1][tid] = EXP2F(m1 - ms);
    }
    __syncthreads();
#pragma unroll
    for (int q = 0; q < 3; ++q) {
        int u = tid + 256 * q;
        if (u < 18 * 32) {
            int ss = u & 31;
            S[u >> 5][ss] = w01[0][ss] * P0[u] + w01[1][ss] * P1[u];
        }
    }
    __syncthreads();

#pragma unroll
    for (int q = 0; q < 2; ++q) {           // choice: 32 samples x 16 dims
        int u = tid + 256 * q;
        int ss = u >> 4, d0 = u & 15;
        out[(size_t)(n0 + ss) * DD + d0] = S[d0][ss] / S[17][ss];
    }
    if (tid < 32) {                          // f_x
        float inv = 1.0f / S[17][tid];
        const float* xr = X + (size_t)(n0 + tid) * DD;
        float dot = 0.0f;
#pragma unroll
        for (int d = 0; d < DD; ++d) dot = fmaf(xr[d], S[d][tid], dot);
        out[(size_t)N * DD + n0 + tid] = (dot - S[16][tid]) * inv;
    }
}

extern "C" void kernel_launch(void* const* d_in, const int* in_sizes, int n_in,
                              void* d_out, int out_size, void* d_ws, size_t ws_size,
                              hipStream_t stream) {
    const float* X = (const float*)d_in[0];
    const float* Y = (const float*)d_in[1];
    const float* B = (const float*)d_in[2];
    float*     out = (float*)d_out;

    const int N = in_sizes[0] / DD;    // 32768
    const int C = in_sizes[2];         // 2048

    char* w = (char*)d_ws;
    unsigned short* YhA = (unsigned short*)(w);
    unsigned short* YlA = (unsigned short*)(w + (size_t)C * DD * 2);
    unsigned short* V3h = (unsigned short*)(w + (size_t)C * DD * 4);
    unsigned*       Bq  = (unsigned*)   (w + (size_t)C * DD * 4 + (size_t)32 * C * 2);
    float*          Part= (float*)      (w + (size_t)(1 << 19));   // 512KB offset, ~4.75MB

    const int prep_threads = C + 32 * C;
    hipLaunchKernelGGL(prep_kernel, dim3((prep_threads + 255) / 256), dim3(256), 0, stream,
                       Y, B, YhA, YlA, V3h, Bq, C);
    hipLaunchKernelGGL(finite_part, dim3(N / 32, 2), dim3(256), 0, stream,
                       X, YhA, YlA, V3h, Bq, Part, N, C);
    hipLaunchKernelGGL(finite_comb, dim3(N / 32), dim3(256), 0, stream,
                       X, Part, out, N);
}